// Round 1
// baseline (995.654 us; speedup 1.0000x reference)
//
#include <hip/hip_runtime.h>
#include <cstdint>
#include <cstddef>

#define BB 64
#define PP 8732
#define OO 32
#define CC 81

// ---------- helpers ----------
__device__ inline unsigned long long shfl_xor_u64(unsigned long long x, int m) {
    unsigned lo = (unsigned)x, hi = (unsigned)(x >> 32);
    lo = (unsigned)__shfl_xor((int)lo, m, 64);
    hi = (unsigned)__shfl_xor((int)hi, m, 64);
    return ((unsigned long long)hi << 32) | lo;
}

// ---------- kernel A1: per-prior best object (argmax over o, first-index ties) ----------
__global__ __launch_bounds__(256) void k_match_prior(
    const float* __restrict__ gt_boxes,      // [B,O,4] coco pixel
    const float4* __restrict__ priors,       // [P] cxcy
    float* __restrict__ ovl, int* __restrict__ obj)
{
    int b = blockIdx.y;
    int p = blockIdx.x * 256 + threadIdx.x;
    __shared__ float bx1[OO], by1[OO], bx2[OO], by2[OO], bar[OO];
    int t = threadIdx.x;
    if (t < OO) {
        const float* g = gt_boxes + ((size_t)b * OO + t) * 4;
        float x1 = g[0] / 224.0f, y1 = g[1] / 224.0f;
        float x2 = (g[0] + g[2]) / 224.0f, y2 = (g[1] + g[3]) / 224.0f;
        bx1[t] = x1; by1[t] = y1; bx2[t] = x2; by2[t] = y2;
        bar[t] = (x2 - x1) * (y2 - y1);
    }
    __syncthreads();
    if (p >= PP) return;
    float4 pr = priors[p];
    float px1 = pr.x - pr.z * 0.5f, py1 = pr.y - pr.w * 0.5f;
    float px2 = pr.x + pr.z * 0.5f, py2 = pr.y + pr.w * 0.5f;
    float parea = (px2 - px1) * (py2 - py1);
    float best = -1.0f; int bo = 0;
    #pragma unroll
    for (int o = 0; o < OO; ++o) {
        float lx = fmaxf(bx1[o], px1), ly = fmaxf(by1[o], py1);
        float rx = fminf(bx2[o], px2), ry = fminf(by2[o], py2);
        float w = fmaxf(rx - lx, 0.0f), h = fmaxf(ry - ly, 0.0f);
        float inter = w * h;
        float iou = inter / (bar[o] + parea - inter);
        if (iou > best) { best = iou; bo = o; }   // strict > : first max (numpy argmax)
    }
    size_t idx = (size_t)b * PP + p;
    ovl[idx] = best;
    obj[idx] = bo;
}

// ---------- kernel A1b: per-object best prior (argmax over p, first-index ties) ----------
__global__ __launch_bounds__(256) void k_match_obj(
    const float* __restrict__ gt_boxes,
    const float4* __restrict__ priors,
    unsigned long long* __restrict__ part)   // [B,O] packed (iou_bits<<32)|(~p)
{
    int chunk = blockIdx.x;   // 0..8
    int o = blockIdx.y;       // 0..31
    int b = blockIdx.z;       // 0..63
    __shared__ float s_box[5];
    if (threadIdx.x == 0) {
        const float* g = gt_boxes + ((size_t)b * OO + o) * 4;
        float x1 = g[0] / 224.0f, y1 = g[1] / 224.0f;
        float x2 = (g[0] + g[2]) / 224.0f, y2 = (g[1] + g[3]) / 224.0f;
        s_box[0] = x1; s_box[1] = y1; s_box[2] = x2; s_box[3] = y2;
        s_box[4] = (x2 - x1) * (y2 - y1);
    }
    __syncthreads();
    float x1 = s_box[0], y1 = s_box[1], x2 = s_box[2], y2 = s_box[3], ba = s_box[4];
    unsigned long long packed = 0ULL;
    #pragma unroll
    for (int k = 0; k < 4; ++k) {
        int p = chunk * 1024 + k * 256 + (int)threadIdx.x;
        if (p < PP) {
            float4 pr = priors[p];
            float px1 = pr.x - pr.z * 0.5f, py1 = pr.y - pr.w * 0.5f;
            float px2 = pr.x + pr.z * 0.5f, py2 = pr.y + pr.w * 0.5f;
            float parea = (px2 - px1) * (py2 - py1);
            float lx = fmaxf(x1, px1), ly = fmaxf(y1, py1);
            float rx = fminf(x2, px2), ry = fminf(y2, py2);
            float w = fmaxf(rx - lx, 0.0f), h = fmaxf(ry - ly, 0.0f);
            float inter = w * h;
            float iou = inter / (ba + parea - inter);     // iou >= 0 always
            unsigned long long pk = ((unsigned long long)__float_as_uint(iou) << 32)
                                  | (unsigned long long)(0xFFFFFFFFu - (unsigned)p);
            if (pk > packed) packed = pk;
        }
    }
    for (int m = 32; m >= 1; m >>= 1) {
        unsigned long long other = shfl_xor_u64(packed, m);
        if (other > packed) packed = other;
    }
    __shared__ unsigned long long s_w[4];
    int wid = threadIdx.x >> 6;
    if ((threadIdx.x & 63) == 0) s_w[wid] = packed;
    __syncthreads();
    if (threadIdx.x == 0) {
        unsigned long long m0 = s_w[0];
        for (int i = 1; i < 4; ++i) if (s_w[i] > m0) m0 = s_w[i];
        atomicMax(&part[b * OO + o], m0);
    }
}

// ---------- kernel A2: forced assignment (sequential o ascending = numpy last-wins) ----------
__global__ void k_force(const unsigned long long* __restrict__ part,
                        float* __restrict__ ovl, int* __restrict__ obj)
{
    int b = blockIdx.x;
    __shared__ int s_pfo[OO];
    int t = threadIdx.x;
    if (t < OO) {
        unsigned long long pk = part[b * OO + t];
        s_pfo[t] = (int)(0xFFFFFFFFu - (unsigned)(pk & 0xFFFFFFFFull));
    }
    __syncthreads();
    if (t == 0) {
        for (int o = 0; o < OO; ++o) {
            int p = s_pfo[o];
            obj[(size_t)b * PP + p] = o;
            ovl[(size_t)b * PP + p] = 1.0f;
        }
    }
}

// ---------- kernel B: cross-entropy + labels + loc loss + ce_neg ----------
__global__ __launch_bounds__(256) void k_ce(
    const float* __restrict__ scores,        // [B,P,C]
    const float4* __restrict__ pred_locs,    // [B,P]
    const float* __restrict__ gt_boxes,
    const int* __restrict__ gt_labels,
    const float4* __restrict__ priors,
    const float* __restrict__ ovl, const int* __restrict__ obj,
    float* __restrict__ ceneg,
    int* __restrict__ n_pos, float* __restrict__ acc)  // acc[0]=pos_ce, acc[1]=sl1
{
    int b = blockIdx.y;
    int group = threadIdx.x >> 4, lane = threadIdx.x & 15;
    int p = blockIdx.x * 16 + group;
    bool pv = p < PP;
    __shared__ float s_posce, s_sl1;
    __shared__ int s_np;
    if (threadIdx.x == 0) { s_posce = 0.f; s_sl1 = 0.f; s_np = 0; }
    __syncthreads();
    int label = 0, ob = 0;
    size_t idx = (size_t)b * PP + (size_t)(pv ? p : 0);
    if (pv) {
        float ov = ovl[idx]; ob = obj[idx];
        label = (ov < 0.5f) ? 0 : gt_labels[b * OO + ob];
    }
    const float* row = scores + idx * CC;
    float v[6];
    float m = -INFINITY;
    #pragma unroll
    for (int k = 0; k < 6; ++k) {
        int c = lane + 16 * k;
        v[k] = (pv && c < CC) ? row[c] : -INFINITY;
        m = fmaxf(m, v[k]);
    }
    for (int s = 8; s >= 1; s >>= 1) m = fmaxf(m, __shfl_xor(m, s, 16));
    float se = 0.f, xl = 0.f;
    #pragma unroll
    for (int k = 0; k < 6; ++k) {
        int c = lane + 16 * k;
        if (c < CC) {
            se += __expf(v[k] - m);
            if (c == label) xl = v[k];
        }
    }
    for (int s = 8; s >= 1; s >>= 1) se += __shfl_xor(se, s, 16);
    for (int s = 8; s >= 1; s >>= 1) xl += __shfl_xor(xl, s, 16);
    if (pv && lane == 0) {
        float ce = m + logf(se) - xl;
        float cn = ce;
        if (label != 0) {
            cn = 0.f;
            float4 pl = pred_locs[idx];
            float4 pr = priors[p];
            const float* g = gt_boxes + ((size_t)b * OO + ob) * 4;
            float x1 = g[0] / 224.0f, y1 = g[1] / 224.0f;
            float x2 = (g[0] + g[2]) / 224.0f, y2 = (g[1] + g[3]) / 224.0f;
            float cx = (x1 + x2) * 0.5f, cy = (y1 + y2) * 0.5f;
            float w = x2 - x1, h = y2 - y1;
            float tx = (cx - pr.x) / (pr.z / 10.0f);
            float ty = (cy - pr.y) / (pr.w / 10.0f);
            float tw = logf(w / pr.z) * 5.0f;
            float th = logf(h / pr.w) * 5.0f;
            float d0 = fabsf(pl.x - tx), d1 = fabsf(pl.y - ty);
            float d2 = fabsf(pl.z - tw), d3 = fabsf(pl.w - th);
            float sl = (d0 < 1.f ? 0.5f * d0 * d0 : d0 - 0.5f)
                     + (d1 < 1.f ? 0.5f * d1 * d1 : d1 - 0.5f)
                     + (d2 < 1.f ? 0.5f * d2 * d2 : d2 - 0.5f)
                     + (d3 < 1.f ? 0.5f * d3 * d3 : d3 - 0.5f);
            atomicAdd(&s_posce, ce);
            atomicAdd(&s_sl1, sl);
            atomicAdd(&s_np, 1);
        }
        ceneg[idx] = cn;
    }
    __syncthreads();
    if (threadIdx.x == 0 && s_np > 0) {
        atomicAdd(&n_pos[b], s_np);
        atomicAdd(&acc[0], s_posce);
        atomicAdd(&acc[1], s_sl1);
    }
}

// ---------- kernel C: exact top-K sum via bit-pattern binary search ----------
__global__ __launch_bounds__(256) void k_topk(
    const float* __restrict__ ceneg, const int* __restrict__ n_pos,
    float* __restrict__ hard)
{
    int b = blockIdx.x;
    __shared__ float sv[PP];
    __shared__ int s_part[4];
    __shared__ float s_fpart[4];
    __shared__ int s_bcast;
    const float* src = ceneg + (size_t)b * PP;
    for (int i = threadIdx.x; i < PP; i += 256) sv[i] = src[i];
    __syncthreads();
    int np = n_pos[b];
    int K = 3 * (np > 1 ? np : 1);
    if (K > PP) K = PP;
    // invariant: cnt_ge(lo) >= K, cnt_ge(hi) < K.  all values >= 0 so uint order == float order
    unsigned lo = 0u, hi = 0x7F800000u;
    while (hi - lo > 1u) {
        unsigned mid = (lo + hi) >> 1;
        float t = __uint_as_float(mid);
        int c = 0;
        for (int i = threadIdx.x; i < PP; i += 256) c += (sv[i] >= t) ? 1 : 0;
        for (int s = 32; s >= 1; s >>= 1) c += __shfl_xor(c, s, 64);
        int wid = threadIdx.x >> 6;
        if ((threadIdx.x & 63) == 0) s_part[wid] = c;
        __syncthreads();
        if (threadIdx.x == 0) s_bcast = s_part[0] + s_part[1] + s_part[2] + s_part[3];
        __syncthreads();
        int cnt = s_bcast;
        if (cnt >= K) lo = mid; else hi = mid;
        __syncthreads();
    }
    float vk = __uint_as_float(lo);   // exact K-th largest value
    float sm = 0.f; int cg = 0;
    for (int i = threadIdx.x; i < PP; i += 256) {
        float x = sv[i];
        if (x > vk) { sm += x; cg++; }
    }
    for (int s = 32; s >= 1; s >>= 1) {
        sm += __shfl_xor(sm, s, 64);
        cg += __shfl_xor(cg, s, 64);
    }
    int wid = threadIdx.x >> 6;
    if ((threadIdx.x & 63) == 0) { s_fpart[wid] = sm; s_part[wid] = cg; }
    __syncthreads();
    if (threadIdx.x == 0) {
        float S = s_fpart[0] + s_fpart[1] + s_fpart[2] + s_fpart[3];
        int CG = s_part[0] + s_part[1] + s_part[2] + s_part[3];
        hard[b] = S + (float)(K - CG) * vk;  // ties at vk handled exactly
    }
}

// ---------- kernel D: final combine ----------
__global__ void k_final(const int* __restrict__ n_pos, const float* __restrict__ hard,
                        const float* __restrict__ acc, float* __restrict__ out)
{
    int t = threadIdx.x;   // 64 threads = 1 wave
    int np = (t < BB) ? n_pos[t] : 0;
    float h = (t < BB) ? hard[t] : 0.f;
    float cl = (t < BB) ? (float)(np > 1 ? np : 1) : 0.f;
    int tp = np; float hs = h; float cls = cl;
    for (int s = 32; s >= 1; s >>= 1) {
        tp += __shfl_xor(tp, s, 64);
        hs += __shfl_xor(hs, s, 64);
        cls += __shfl_xor(cls, s, 64);
    }
    if (t == 0) {
        float conf = (hs + acc[0]) / cls;
        float loc = 0.f;
        if (tp > 0) {
            int den = tp * 4; if (den < 1) den = 1;
            loc = acc[1] / (float)den;
        }
        out[0] = conf + loc;
    }
}

extern "C" void kernel_launch(void* const* d_in, const int* in_sizes, int n_in,
                              void* d_out, int out_size, void* d_ws, size_t ws_size,
                              hipStream_t stream)
{
    const float* pred_locs   = (const float*)d_in[0];
    const float* pred_scores = (const float*)d_in[1];
    const float* gt_boxes    = (const float*)d_in[2];
    const int*   gt_labels   = (const int*)d_in[3];
    const float* priors      = (const float*)d_in[4];

    char* ws = (char*)d_ws;
    const size_t npf = (size_t)BB * PP;          // 558,848
    float* ovl   = (float*)(ws);
    int*   obj   = (int*)  (ws + 4 * npf);
    float* ceneg = (float*)(ws + 8 * npf);
    unsigned long long* part = (unsigned long long*)(ws + 12 * npf);
    int*   n_pos = (int*)  (ws + 12 * npf + 8 * BB * OO);
    float* hard  = (float*)(ws + 12 * npf + 8 * BB * OO + 4 * BB);
    float* acc   = (float*)(ws + 12 * npf + 8 * BB * OO + 8 * BB);

    // zero: part[B*O] u64 + n_pos[B] + hard[B] + acc[2]
    hipMemsetAsync(ws + 12 * npf, 0, 8 * BB * OO + 8 * BB + 8, stream);

    dim3 gA1((PP + 255) / 256, BB);
    k_match_prior<<<gA1, 256, 0, stream>>>(gt_boxes, (const float4*)priors, ovl, obj);

    dim3 gA1b((PP + 1023) / 1024, OO, BB);
    k_match_obj<<<gA1b, 256, 0, stream>>>(gt_boxes, (const float4*)priors, part);

    k_force<<<BB, 64, 0, stream>>>(part, ovl, obj);

    dim3 gB((PP + 15) / 16, BB);
    k_ce<<<gB, 256, 0, stream>>>(pred_scores, (const float4*)pred_locs, gt_boxes, gt_labels,
                                 (const float4*)priors, ovl, obj, ceneg, n_pos, acc);

    k_topk<<<BB, 256, 0, stream>>>(ceneg, n_pos, hard);

    k_final<<<1, 64, 0, stream>>>(n_pos, hard, acc, (float*)d_out);
}

// Round 2
// 352.208 us; speedup vs baseline: 2.8269x; 2.8269x over previous
//
#include <hip/hip_runtime.h>
#include <cstdint>
#include <cstddef>

#define BB 64
#define PP 8732
#define OO 32
#define CC 81
#define NB 546   // (PP+15)/16 blocks per image in k_ce

// ---------- helpers ----------
__device__ inline unsigned long long shfl_xor_u64(unsigned long long x, int m) {
    unsigned lo = (unsigned)x, hi = (unsigned)(x >> 32);
    lo = (unsigned)__shfl_xor((int)lo, m, 64);
    hi = (unsigned)__shfl_xor((int)hi, m, 64);
    return ((unsigned long long)hi << 32) | lo;
}

// ---------- kernel A1: per-prior best object (argmax over o, first-index ties) ----------
__global__ __launch_bounds__(256) void k_match_prior(
    const float* __restrict__ gt_boxes,      // [B,O,4] coco pixel
    const float4* __restrict__ priors,       // [P] cxcy
    float* __restrict__ ovl, int* __restrict__ obj)
{
    int b = blockIdx.y;
    int p = blockIdx.x * 256 + threadIdx.x;
    __shared__ float bx1[OO], by1[OO], bx2[OO], by2[OO], bar[OO];
    int t = threadIdx.x;
    if (t < OO) {
        const float* g = gt_boxes + ((size_t)b * OO + t) * 4;
        float x1 = g[0] / 224.0f, y1 = g[1] / 224.0f;
        float x2 = (g[0] + g[2]) / 224.0f, y2 = (g[1] + g[3]) / 224.0f;
        bx1[t] = x1; by1[t] = y1; bx2[t] = x2; by2[t] = y2;
        bar[t] = (x2 - x1) * (y2 - y1);
    }
    __syncthreads();
    if (p >= PP) return;
    float4 pr = priors[p];
    float px1 = pr.x - pr.z * 0.5f, py1 = pr.y - pr.w * 0.5f;
    float px2 = pr.x + pr.z * 0.5f, py2 = pr.y + pr.w * 0.5f;
    float parea = (px2 - px1) * (py2 - py1);
    float best = -1.0f; int bo = 0;
    #pragma unroll
    for (int o = 0; o < OO; ++o) {
        float lx = fmaxf(bx1[o], px1), ly = fmaxf(by1[o], py1);
        float rx = fminf(bx2[o], px2), ry = fminf(by2[o], py2);
        float w = fmaxf(rx - lx, 0.0f), h = fmaxf(ry - ly, 0.0f);
        float inter = w * h;
        float iou = inter / (bar[o] + parea - inter);
        if (iou > best) { best = iou; bo = o; }   // strict > : first max (numpy argmax)
    }
    size_t idx = (size_t)b * PP + p;
    ovl[idx] = best;
    obj[idx] = bo;
}

// ---------- kernel A1b: per-object best prior (argmax over p, first-index ties) ----------
__global__ __launch_bounds__(256) void k_match_obj(
    const float* __restrict__ gt_boxes,
    const float4* __restrict__ priors,
    unsigned long long* __restrict__ part)   // [B,O] packed (iou_bits<<32)|(~p)
{
    int chunk = blockIdx.x;   // 0..8
    int o = blockIdx.y;       // 0..31
    int b = blockIdx.z;       // 0..63
    __shared__ float s_box[5];
    if (threadIdx.x == 0) {
        const float* g = gt_boxes + ((size_t)b * OO + o) * 4;
        float x1 = g[0] / 224.0f, y1 = g[1] / 224.0f;
        float x2 = (g[0] + g[2]) / 224.0f, y2 = (g[1] + g[3]) / 224.0f;
        s_box[0] = x1; s_box[1] = y1; s_box[2] = x2; s_box[3] = y2;
        s_box[4] = (x2 - x1) * (y2 - y1);
    }
    __syncthreads();
    float x1 = s_box[0], y1 = s_box[1], x2 = s_box[2], y2 = s_box[3], ba = s_box[4];
    unsigned long long packed = 0ULL;
    #pragma unroll
    for (int k = 0; k < 4; ++k) {
        int p = chunk * 1024 + k * 256 + (int)threadIdx.x;
        if (p < PP) {
            float4 pr = priors[p];
            float px1 = pr.x - pr.z * 0.5f, py1 = pr.y - pr.w * 0.5f;
            float px2 = pr.x + pr.z * 0.5f, py2 = pr.y + pr.w * 0.5f;
            float parea = (px2 - px1) * (py2 - py1);
            float lx = fmaxf(x1, px1), ly = fmaxf(y1, py1);
            float rx = fminf(x2, px2), ry = fminf(y2, py2);
            float w = fmaxf(rx - lx, 0.0f), h = fmaxf(ry - ly, 0.0f);
            float inter = w * h;
            float iou = inter / (ba + parea - inter);     // iou >= 0 always
            unsigned long long pk = ((unsigned long long)__float_as_uint(iou) << 32)
                                  | (unsigned long long)(0xFFFFFFFFu - (unsigned)p);
            if (pk > packed) packed = pk;
        }
    }
    for (int m = 32; m >= 1; m >>= 1) {
        unsigned long long other = shfl_xor_u64(packed, m);
        if (other > packed) packed = other;
    }
    __shared__ unsigned long long s_w[4];
    int wid = threadIdx.x >> 6;
    if ((threadIdx.x & 63) == 0) s_w[wid] = packed;
    __syncthreads();
    if (threadIdx.x == 0) {
        unsigned long long m0 = s_w[0];
        for (int i = 1; i < 4; ++i) if (s_w[i] > m0) m0 = s_w[i];
        atomicMax(&part[b * OO + o], m0);   // 2048 addresses, 9 blocks each — uncontended
    }
}

// ---------- kernel A2: forced assignment (sequential o ascending = numpy last-wins) ----------
__global__ void k_force(const unsigned long long* __restrict__ part,
                        float* __restrict__ ovl, int* __restrict__ obj)
{
    int b = blockIdx.x;
    __shared__ int s_pfo[OO];
    int t = threadIdx.x;
    if (t < OO) {
        unsigned long long pk = part[b * OO + t];
        s_pfo[t] = (int)(0xFFFFFFFFu - (unsigned)(pk & 0xFFFFFFFFull));
    }
    __syncthreads();
    if (t == 0) {
        for (int o = 0; o < OO; ++o) {
            int p = s_pfo[o];
            obj[(size_t)b * PP + p] = o;
            ovl[(size_t)b * PP + p] = 1.0f;
        }
    }
}

// ---------- kernel B: cross-entropy + labels + loc loss + ce_neg ----------
// Per-block partials to dedicated slots — ZERO global atomics (was the 719us serializer).
__global__ __launch_bounds__(256) void k_ce(
    const float* __restrict__ scores,        // [B,P,C]
    const float4* __restrict__ pred_locs,    // [B,P]
    const float* __restrict__ gt_boxes,
    const int* __restrict__ gt_labels,
    const float4* __restrict__ priors,
    const float* __restrict__ ovl, const int* __restrict__ obj,
    float* __restrict__ ceneg,
    float* __restrict__ pp_posce, float* __restrict__ pp_sl1,
    int* __restrict__ pp_np)
{
    int b = blockIdx.y;
    int group = threadIdx.x >> 4, lane = threadIdx.x & 15;
    int p = blockIdx.x * 16 + group;
    bool pv = p < PP;
    __shared__ float s_posce, s_sl1;
    __shared__ int s_np;
    if (threadIdx.x == 0) { s_posce = 0.f; s_sl1 = 0.f; s_np = 0; }
    __syncthreads();
    int label = 0, ob = 0;
    size_t idx = (size_t)b * PP + (size_t)(pv ? p : 0);
    if (pv) {
        float ov = ovl[idx]; ob = obj[idx];
        label = (ov < 0.5f) ? 0 : gt_labels[b * OO + ob];
    }
    const float* row = scores + idx * CC;
    float v[6];
    float m = -INFINITY;
    #pragma unroll
    for (int k = 0; k < 6; ++k) {
        int c = lane + 16 * k;
        v[k] = (pv && c < CC) ? row[c] : -INFINITY;
        m = fmaxf(m, v[k]);
    }
    for (int s = 8; s >= 1; s >>= 1) m = fmaxf(m, __shfl_xor(m, s, 16));
    float se = 0.f, xl = 0.f;
    #pragma unroll
    for (int k = 0; k < 6; ++k) {
        int c = lane + 16 * k;
        if (c < CC) {
            se += __expf(v[k] - m);
            if (c == label) xl = v[k];
        }
    }
    for (int s = 8; s >= 1; s >>= 1) se += __shfl_xor(se, s, 16);
    for (int s = 8; s >= 1; s >>= 1) xl += __shfl_xor(xl, s, 16);
    if (pv && lane == 0) {
        float ce = m + logf(se) - xl;
        float cn = ce;
        if (label != 0) {
            cn = 0.f;
            float4 pl = pred_locs[idx];
            float4 pr = priors[p];
            const float* g = gt_boxes + ((size_t)b * OO + ob) * 4;
            float x1 = g[0] / 224.0f, y1 = g[1] / 224.0f;
            float x2 = (g[0] + g[2]) / 224.0f, y2 = (g[1] + g[3]) / 224.0f;
            float cx = (x1 + x2) * 0.5f, cy = (y1 + y2) * 0.5f;
            float w = x2 - x1, h = y2 - y1;
            float tx = (cx - pr.x) / (pr.z / 10.0f);
            float ty = (cy - pr.y) / (pr.w / 10.0f);
            float tw = logf(w / pr.z) * 5.0f;
            float th = logf(h / pr.w) * 5.0f;
            float d0 = fabsf(pl.x - tx), d1 = fabsf(pl.y - ty);
            float d2 = fabsf(pl.z - tw), d3 = fabsf(pl.w - th);
            float sl = (d0 < 1.f ? 0.5f * d0 * d0 : d0 - 0.5f)
                     + (d1 < 1.f ? 0.5f * d1 * d1 : d1 - 0.5f)
                     + (d2 < 1.f ? 0.5f * d2 * d2 : d2 - 0.5f)
                     + (d3 < 1.f ? 0.5f * d3 * d3 : d3 - 0.5f);
            atomicAdd(&s_posce, ce);   // LDS atomic — per-CU, cheap
            atomicAdd(&s_sl1, sl);
            atomicAdd(&s_np, 1);
        }
        ceneg[idx] = cn;
    }
    __syncthreads();
    if (threadIdx.x == 0) {
        int slot = b * NB + blockIdx.x;   // dedicated slot: no atomics, no contention
        pp_posce[slot] = s_posce;
        pp_sl1[slot]   = s_sl1;
        pp_np[slot]    = s_np;
    }
}

// ---------- kernel B2: fold per-block partials into per-image sums ----------
__global__ __launch_bounds__(256) void k_reduce(
    const float* __restrict__ pp_posce, const float* __restrict__ pp_sl1,
    const int* __restrict__ pp_np,
    float* __restrict__ posce_b, float* __restrict__ sl1_b, int* __restrict__ n_pos)
{
    int b = blockIdx.x;
    float pc = 0.f, sl = 0.f; int np = 0;
    for (int i = threadIdx.x; i < NB; i += 256) {
        int slot = b * NB + i;
        pc += pp_posce[slot]; sl += pp_sl1[slot]; np += pp_np[slot];
    }
    for (int s = 32; s >= 1; s >>= 1) {
        pc += __shfl_xor(pc, s, 64);
        sl += __shfl_xor(sl, s, 64);
        np += __shfl_xor(np, s, 64);
    }
    __shared__ float s_pc[4], s_sl[4];
    __shared__ int s_n[4];
    int wid = threadIdx.x >> 6;
    if ((threadIdx.x & 63) == 0) { s_pc[wid] = pc; s_sl[wid] = sl; s_n[wid] = np; }
    __syncthreads();
    if (threadIdx.x == 0) {
        posce_b[b] = s_pc[0] + s_pc[1] + s_pc[2] + s_pc[3];
        sl1_b[b]   = s_sl[0] + s_sl[1] + s_sl[2] + s_sl[3];
        n_pos[b]   = s_n[0] + s_n[1] + s_n[2] + s_n[3];
    }
}

// ---------- kernel C: exact top-K sum via bit-pattern binary search ----------
__global__ __launch_bounds__(256) void k_topk(
    const float* __restrict__ ceneg, const int* __restrict__ n_pos,
    float* __restrict__ hard)
{
    int b = blockIdx.x;
    __shared__ float sv[PP];
    __shared__ int s_part[4];
    __shared__ float s_fpart[4];
    __shared__ int s_bcast;
    const float* src = ceneg + (size_t)b * PP;
    for (int i = threadIdx.x; i < PP; i += 256) sv[i] = src[i];
    __syncthreads();
    int np = n_pos[b];
    int K = 3 * (np > 1 ? np : 1);
    if (K > PP) K = PP;
    // invariant: cnt_ge(lo) >= K, cnt_ge(hi) < K.  all values >= 0 so uint order == float order
    unsigned lo = 0u, hi = 0x7F800000u;
    while (hi - lo > 1u) {
        unsigned mid = (lo + hi) >> 1;
        float t = __uint_as_float(mid);
        int c = 0;
        for (int i = threadIdx.x; i < PP; i += 256) c += (sv[i] >= t) ? 1 : 0;
        for (int s = 32; s >= 1; s >>= 1) c += __shfl_xor(c, s, 64);
        int wid = threadIdx.x >> 6;
        if ((threadIdx.x & 63) == 0) s_part[wid] = c;
        __syncthreads();
        if (threadIdx.x == 0) s_bcast = s_part[0] + s_part[1] + s_part[2] + s_part[3];
        __syncthreads();
        int cnt = s_bcast;
        if (cnt >= K) lo = mid; else hi = mid;
        __syncthreads();
    }
    float vk = __uint_as_float(lo);   // exact K-th largest value
    float sm = 0.f; int cg = 0;
    for (int i = threadIdx.x; i < PP; i += 256) {
        float x = sv[i];
        if (x > vk) { sm += x; cg++; }
    }
    for (int s = 32; s >= 1; s >>= 1) {
        sm += __shfl_xor(sm, s, 64);
        cg += __shfl_xor(cg, s, 64);
    }
    int wid = threadIdx.x >> 6;
    if ((threadIdx.x & 63) == 0) { s_fpart[wid] = sm; s_part[wid] = cg; }
    __syncthreads();
    if (threadIdx.x == 0) {
        float S = s_fpart[0] + s_fpart[1] + s_fpart[2] + s_fpart[3];
        int CG = s_part[0] + s_part[1] + s_part[2] + s_part[3];
        hard[b] = S + (float)(K - CG) * vk;  // ties at vk handled exactly
    }
}

// ---------- kernel D: final combine ----------
__global__ void k_final(const int* __restrict__ n_pos, const float* __restrict__ hard,
                        const float* __restrict__ posce_b, const float* __restrict__ sl1_b,
                        float* __restrict__ out)
{
    int t = threadIdx.x;   // 64 threads = 1 wave
    int np = (t < BB) ? n_pos[t] : 0;
    float h = (t < BB) ? hard[t] : 0.f;
    float pc = (t < BB) ? posce_b[t] : 0.f;
    float sl = (t < BB) ? sl1_b[t] : 0.f;
    float cl = (t < BB) ? (float)(np > 1 ? np : 1) : 0.f;
    int tp = np; float hs = h; float cls = cl;
    for (int s = 32; s >= 1; s >>= 1) {
        tp  += __shfl_xor(tp, s, 64);
        hs  += __shfl_xor(hs, s, 64);
        cls += __shfl_xor(cls, s, 64);
        pc  += __shfl_xor(pc, s, 64);
        sl  += __shfl_xor(sl, s, 64);
    }
    if (t == 0) {
        float conf = (hs + pc) / cls;
        float loc = 0.f;
        if (tp > 0) {
            int den = tp * 4; if (den < 1) den = 1;
            loc = sl / (float)den;
        }
        out[0] = conf + loc;
    }
}

extern "C" void kernel_launch(void* const* d_in, const int* in_sizes, int n_in,
                              void* d_out, int out_size, void* d_ws, size_t ws_size,
                              hipStream_t stream)
{
    const float* pred_locs   = (const float*)d_in[0];
    const float* pred_scores = (const float*)d_in[1];
    const float* gt_boxes    = (const float*)d_in[2];
    const int*   gt_labels   = (const int*)d_in[3];
    const float* priors      = (const float*)d_in[4];

    char* ws = (char*)d_ws;
    const size_t npf = (size_t)BB * PP;          // 558,848
    const size_t nslots = (size_t)BB * NB;       // 34,944
    size_t off = 0;
    float* ovl   = (float*)(ws + off); off += 4 * npf;
    int*   obj   = (int*)  (ws + off); off += 4 * npf;
    float* ceneg = (float*)(ws + off); off += 4 * npf;
    unsigned long long* part = (unsigned long long*)(ws + off);
    size_t part_off = off; off += 8 * (size_t)BB * OO;
    float* pp_posce = (float*)(ws + off); off += 4 * nslots;
    float* pp_sl1   = (float*)(ws + off); off += 4 * nslots;
    int*   pp_np    = (int*)  (ws + off); off += 4 * nslots;
    float* posce_b  = (float*)(ws + off); off += 4 * BB;
    float* sl1_b    = (float*)(ws + off); off += 4 * BB;
    int*   n_pos    = (int*)  (ws + off); off += 4 * BB;
    float* hard     = (float*)(ws + off); off += 4 * BB;

    // only part[] needs zeroing (atomicMax accumulator); everything else is fully written
    hipMemsetAsync(ws + part_off, 0, 8 * (size_t)BB * OO, stream);

    dim3 gA1((PP + 255) / 256, BB);
    k_match_prior<<<gA1, 256, 0, stream>>>(gt_boxes, (const float4*)priors, ovl, obj);

    dim3 gA1b((PP + 1023) / 1024, OO, BB);
    k_match_obj<<<gA1b, 256, 0, stream>>>(gt_boxes, (const float4*)priors, part);

    k_force<<<BB, 64, 0, stream>>>(part, ovl, obj);

    dim3 gB(NB, BB);
    k_ce<<<gB, 256, 0, stream>>>(pred_scores, (const float4*)pred_locs, gt_boxes, gt_labels,
                                 (const float4*)priors, ovl, obj, ceneg,
                                 pp_posce, pp_sl1, pp_np);

    k_reduce<<<BB, 256, 0, stream>>>(pp_posce, pp_sl1, pp_np, posce_b, sl1_b, n_pos);

    k_topk<<<BB, 256, 0, stream>>>(ceneg, n_pos, hard);

    k_final<<<1, 64, 0, stream>>>(n_pos, hard, posce_b, sl1_b, (float*)d_out);
}

// Round 3
// 314.459 us; speedup vs baseline: 3.1662x; 1.1200x over previous
//
#include <hip/hip_runtime.h>
#include <cstdint>
#include <cstddef>

#define BB 64
#define PP 8732
#define OO 32
#define CC 81
#define NBM 35    // k_match blocks per image (ceil(8732/256))
#define NB2 273   // k_ce blocks-x per image (32 priors each; 273*32=8736)

// ---------- kernel A: per-prior best object + per-block per-object best prior ----------
__global__ __launch_bounds__(256) void k_match(
    const float* __restrict__ gt_boxes,      // [B,O,4] coco pixel
    const float4* __restrict__ priors,       // [P] cxcy
    float* __restrict__ ovl, int* __restrict__ obj,
    unsigned long long* __restrict__ part)   // [B,NBM,O] packed (iou_bits<<32)|(~p)
{
    int b = blockIdx.y, blk = blockIdx.x;
    int tid = threadIdx.x;
    int p = blk * 256 + tid;
    bool pv = p < PP;
    __shared__ float bx1[OO], by1[OO], bx2[OO], by2[OO], bar[OO];
    __shared__ float mat[OO][264];           // stride 264 -> 2-way banks max (free)
    __shared__ unsigned long long po[OO][8];
    if (tid < OO) {
        const float* g = gt_boxes + ((size_t)b * OO + tid) * 4;
        float x1 = g[0] / 224.0f, y1 = g[1] / 224.0f;
        float x2 = (g[0] + g[2]) / 224.0f, y2 = (g[1] + g[3]) / 224.0f;
        bx1[tid] = x1; by1[tid] = y1; bx2[tid] = x2; by2[tid] = y2;
        bar[tid] = (x2 - x1) * (y2 - y1);
    }
    __syncthreads();
    float4 pr = priors[pv ? p : 0];
    float px1 = pr.x - pr.z * 0.5f, py1 = pr.y - pr.w * 0.5f;
    float px2 = pr.x + pr.z * 0.5f, py2 = pr.y + pr.w * 0.5f;
    float parea = (px2 - px1) * (py2 - py1);
    float best = -1.0f; int bo = 0;
    #pragma unroll
    for (int o = 0; o < OO; ++o) {
        float lx = fmaxf(bx1[o], px1), ly = fmaxf(by1[o], py1);
        float rx = fminf(bx2[o], px2), ry = fminf(by2[o], py2);
        float w = fmaxf(rx - lx, 0.0f), h = fmaxf(ry - ly, 0.0f);
        float inter = w * h;
        float iou = inter / (bar[o] + parea - inter);
        iou = pv ? iou : 0.0f;               // invalid priors can't win (and have largest p)
        mat[o][tid] = iou;
        if (iou > best) { best = iou; bo = o; }   // strict > : first max (numpy argmax)
    }
    if (pv) {
        size_t idx = (size_t)b * PP + p;
        ovl[idx] = best;
        obj[idx] = bo;
    }
    __syncthreads();
    // per-object partial argmax over this block's 256 priors
    {
        int o = tid >> 3, j = tid & 7;
        float bv = -1.0f; int bt = 0;
        #pragma unroll
        for (int k = 0; k < 32; ++k) {
            int t = j + 8 * k;               // bank-friendly stride, order-free (we pack index)
            float v = mat[o][t];
            if (v > bv) { bv = v; bt = t; }
        }
        unsigned pg = (unsigned)(blk * 256 + bt);
        po[o][j] = ((unsigned long long)__float_as_uint(bv) << 32)
                 | (unsigned long long)(0xFFFFFFFFu - pg);
    }
    __syncthreads();
    if (tid < OO) {
        unsigned long long m = po[tid][0];
        #pragma unroll
        for (int j = 1; j < 8; ++j) if (po[tid][j] > m) m = po[tid][j];
        part[((size_t)b * NBM + blk) * OO + tid] = m;
    }
}

// ---------- kernel A2: fold partials + forced assignment (ascending o = numpy last-wins) ----------
__global__ void k_force(const unsigned long long* __restrict__ part,
                        float* __restrict__ ovl, int* __restrict__ obj)
{
    int b = blockIdx.x;
    __shared__ int s_pfo[OO];
    int t = threadIdx.x;
    if (t < OO) {
        unsigned long long m = part[((size_t)b * NBM + 0) * OO + t];
        for (int blk = 1; blk < NBM; ++blk) {
            unsigned long long v = part[((size_t)b * NBM + blk) * OO + t];
            if (v > m) m = v;                // packed max: larger iou, then smaller p
        }
        s_pfo[t] = (int)(0xFFFFFFFFu - (unsigned)(m & 0xFFFFFFFFull));
    }
    __syncthreads();
    if (t == 0) {
        for (int o = 0; o < OO; ++o) {
            int p = s_pfo[o];
            obj[(size_t)b * PP + p] = o;
            ovl[(size_t)b * PP + p] = 1.0f;
        }
    }
}

// ---------- kernel B: CE (no max-sub) + loc loss, 2 priors per 16-lane group ----------
__global__ __launch_bounds__(256) void k_ce(
    const float* __restrict__ scores,        // [B,P,C]
    const float4* __restrict__ pred_locs,
    const float* __restrict__ gt_boxes,
    const int* __restrict__ gt_labels,
    const float4* __restrict__ priors,
    const float* __restrict__ ovl, const int* __restrict__ obj,
    float* __restrict__ ceneg,
    float* __restrict__ pp_posce, float* __restrict__ pp_sl1,
    int* __restrict__ pp_np)
{
    int b = blockIdx.y;
    int group = threadIdx.x >> 4, lane = threadIdx.x & 15;
    int p0 = blockIdx.x * 32 + group;
    int p1 = p0 + 16;
    bool v0 = p0 < PP, v1 = p1 < PP;
    size_t i0 = (size_t)b * PP + (size_t)(v0 ? p0 : 0);
    size_t i1 = (size_t)b * PP + (size_t)(v1 ? p1 : 0);
    __shared__ float s_posce, s_sl1;
    __shared__ int s_np;
    if (threadIdx.x == 0) { s_posce = 0.f; s_sl1 = 0.f; s_np = 0; }
    __syncthreads();
    int lab0 = 0, ob0 = 0, lab1 = 0, ob1 = 0;
    if (v0) { float ov = ovl[i0]; ob0 = obj[i0]; lab0 = (ov < 0.5f) ? 0 : gt_labels[b * OO + ob0]; }
    if (v1) { float ov = ovl[i1]; ob1 = obj[i1]; lab1 = (ov < 0.5f) ? 0 : gt_labels[b * OO + ob1]; }
    const float* r0 = scores + i0 * CC;
    const float* r1 = scores + i1 * CC;
    float a0[6], a1[6];
    #pragma unroll
    for (int k = 0; k < 6; ++k) {
        int c = lane + 16 * k;
        bool cv = c < CC;
        a0[k] = (v0 && cv) ? r0[c] : -INFINITY;
        a1[k] = (v1 && cv) ? r1[c] : -INFINITY;
    }
    float se0 = 0.f, xl0 = 0.f, se1 = 0.f, xl1 = 0.f;
    #pragma unroll
    for (int k = 0; k < 6; ++k) {
        int c = lane + 16 * k;
        if (c < CC) {
            se0 += __expf(a0[k]); if (c == lab0) xl0 = a0[k];
            se1 += __expf(a1[k]); if (c == lab1) xl1 = a1[k];
        }
    }
    #pragma unroll
    for (int s = 8; s >= 1; s >>= 1) {
        se0 += __shfl_xor(se0, s, 16);
        xl0 += __shfl_xor(xl0, s, 16);
        se1 += __shfl_xor(se1, s, 16);
        xl1 += __shfl_xor(xl1, s, 16);
    }
    if (lane == 0) {
        #pragma unroll
        for (int pass = 0; pass < 2; ++pass) {
            bool vv = pass ? v1 : v0;
            if (!vv) continue;
            size_t idx = pass ? i1 : i0;
            int lab = pass ? lab1 : lab0;
            int ob  = pass ? ob1 : ob0;
            int p   = pass ? p1 : p0;
            float se = pass ? se1 : se0;
            float xl = pass ? xl1 : xl0;
            float ce = fmaxf(__logf(se) - xl, 0.0f);
            float cn = ce;
            if (lab != 0) {
                cn = 0.f;
                float4 pl = pred_locs[idx];
                float4 pq = priors[p];
                const float* g = gt_boxes + ((size_t)b * OO + ob) * 4;
                float x1 = g[0] / 224.0f, y1 = g[1] / 224.0f;
                float x2 = (g[0] + g[2]) / 224.0f, y2 = (g[1] + g[3]) / 224.0f;
                float cx = (x1 + x2) * 0.5f, cy = (y1 + y2) * 0.5f;
                float w = x2 - x1, h = y2 - y1;
                float tx = (cx - pq.x) / (pq.z / 10.0f);
                float ty = (cy - pq.y) / (pq.w / 10.0f);
                float tw = __logf(w / pq.z) * 5.0f;
                float th = __logf(h / pq.w) * 5.0f;
                float d0 = fabsf(pl.x - tx), d1 = fabsf(pl.y - ty);
                float d2 = fabsf(pl.z - tw), d3 = fabsf(pl.w - th);
                float sl = (d0 < 1.f ? 0.5f * d0 * d0 : d0 - 0.5f)
                         + (d1 < 1.f ? 0.5f * d1 * d1 : d1 - 0.5f)
                         + (d2 < 1.f ? 0.5f * d2 * d2 : d2 - 0.5f)
                         + (d3 < 1.f ? 0.5f * d3 * d3 : d3 - 0.5f);
                atomicAdd(&s_posce, ce);   // LDS atomics — per-CU, cheap
                atomicAdd(&s_sl1, sl);
                atomicAdd(&s_np, 1);
            }
            ceneg[idx] = cn;
        }
    }
    __syncthreads();
    if (threadIdx.x == 0) {
        int slot = b * NB2 + blockIdx.x;   // dedicated slot: zero global atomics
        pp_posce[slot] = s_posce;
        pp_sl1[slot]   = s_sl1;
        pp_np[slot]    = s_np;
    }
}

// ---------- kernel C: fold partials + exact top-K via bit-pattern binary search ----------
__global__ __launch_bounds__(512) void k_topk(
    const float* __restrict__ ceneg,
    const float* __restrict__ pp_posce, const float* __restrict__ pp_sl1,
    const int* __restrict__ pp_np,
    float* __restrict__ hard, float* __restrict__ posce_b,
    float* __restrict__ sl1_b, int* __restrict__ n_pos)
{
    int b = blockIdx.x, tid = threadIdx.x;
    __shared__ float4 sv4[PP / 4];           // 8732/4 = 2183
    __shared__ int s_i[8];
    __shared__ float s_f[8], s_f2[8];
    __shared__ int s_bcast;
    // fold per-block partials for this image
    float pc = 0.f, sl = 0.f; int np = 0;
    for (int i = tid; i < NB2; i += 512) {
        pc += pp_posce[b * NB2 + i];
        sl += pp_sl1[b * NB2 + i];
        np += pp_np[b * NB2 + i];
    }
    #pragma unroll
    for (int s = 32; s >= 1; s >>= 1) {
        pc += __shfl_xor(pc, s, 64);
        sl += __shfl_xor(sl, s, 64);
        np += __shfl_xor(np, s, 64);
    }
    int wid = tid >> 6;
    if ((tid & 63) == 0) { s_i[wid] = np; s_f[wid] = pc; s_f2[wid] = sl; }
    // stage ce_neg into LDS (float4)
    const float4* src = (const float4*)(ceneg + (size_t)b * PP);
    for (int i = tid; i < PP / 4; i += 512) sv4[i] = src[i];
    __syncthreads();
    if (tid == 0) {
        int n = 0; float fp = 0.f, fs = 0.f;
        #pragma unroll
        for (int k = 0; k < 8; ++k) { n += s_i[k]; fp += s_f[k]; fs += s_f2[k]; }
        n_pos[b] = n; posce_b[b] = fp; sl1_b[b] = fs;
        s_bcast = n;
    }
    __syncthreads();
    np = s_bcast;
    int K = 3 * (np > 1 ? np : 1);
    if (K > PP) K = PP;
    // invariant: cnt_ge(lo) >= K, cnt_ge(hi) < K; all values >= 0 so uint order == float order
    unsigned lo = 0u, hi = 0x7F800000u;
    while (hi - lo > 1u) {
        unsigned mid = (lo + hi) >> 1;
        float t = __uint_as_float(mid);
        int c = 0;
        for (int i = tid; i < PP / 4; i += 512) {
            float4 q = sv4[i];
            c += (q.x >= t) + (q.y >= t) + (q.z >= t) + (q.w >= t);
        }
        #pragma unroll
        for (int s = 32; s >= 1; s >>= 1) c += __shfl_xor(c, s, 64);
        if ((tid & 63) == 0) s_i[wid] = c;
        __syncthreads();
        if (tid == 0) {
            int n = 0;
            #pragma unroll
            for (int k = 0; k < 8; ++k) n += s_i[k];
            s_bcast = n;
        }
        __syncthreads();
        int cnt = s_bcast;
        if (cnt >= K) lo = mid; else hi = mid;
        __syncthreads();
    }
    float vk = __uint_as_float(lo);   // exact K-th largest value
    float sm = 0.f; int cg = 0;
    for (int i = tid; i < PP / 4; i += 512) {
        float4 q = sv4[i];
        if (q.x > vk) { sm += q.x; cg++; }
        if (q.y > vk) { sm += q.y; cg++; }
        if (q.z > vk) { sm += q.z; cg++; }
        if (q.w > vk) { sm += q.w; cg++; }
    }
    #pragma unroll
    for (int s = 32; s >= 1; s >>= 1) {
        sm += __shfl_xor(sm, s, 64);
        cg += __shfl_xor(cg, s, 64);
    }
    if ((tid & 63) == 0) { s_f[wid] = sm; s_i[wid] = cg; }
    __syncthreads();
    if (tid == 0) {
        float S = 0.f; int CG = 0;
        #pragma unroll
        for (int k = 0; k < 8; ++k) { S += s_f[k]; CG += s_i[k]; }
        hard[b] = S + (float)(K - CG) * vk;  // ties at vk handled exactly
    }
}

// ---------- kernel D: final combine ----------
__global__ void k_final(const int* __restrict__ n_pos, const float* __restrict__ hard,
                        const float* __restrict__ posce_b, const float* __restrict__ sl1_b,
                        float* __restrict__ out)
{
    int t = threadIdx.x;   // 64 threads = 1 wave
    int np = (t < BB) ? n_pos[t] : 0;
    float h  = (t < BB) ? hard[t] : 0.f;
    float pc = (t < BB) ? posce_b[t] : 0.f;
    float sl = (t < BB) ? sl1_b[t] : 0.f;
    float cl = (t < BB) ? (float)(np > 1 ? np : 1) : 0.f;
    int tp = np; float hs = h; float cls = cl;
    #pragma unroll
    for (int s = 32; s >= 1; s >>= 1) {
        tp  += __shfl_xor(tp, s, 64);
        hs  += __shfl_xor(hs, s, 64);
        cls += __shfl_xor(cls, s, 64);
        pc  += __shfl_xor(pc, s, 64);
        sl  += __shfl_xor(sl, s, 64);
    }
    if (t == 0) {
        float conf = (hs + pc) / cls;
        float loc = 0.f;
        if (tp > 0) {
            int den = tp * 4; if (den < 1) den = 1;
            loc = sl / (float)den;
        }
        out[0] = conf + loc;
    }
}

extern "C" void kernel_launch(void* const* d_in, const int* in_sizes, int n_in,
                              void* d_out, int out_size, void* d_ws, size_t ws_size,
                              hipStream_t stream)
{
    const float* pred_locs   = (const float*)d_in[0];
    const float* pred_scores = (const float*)d_in[1];
    const float* gt_boxes    = (const float*)d_in[2];
    const int*   gt_labels   = (const int*)d_in[3];
    const float* priors      = (const float*)d_in[4];

    char* ws = (char*)d_ws;
    const size_t npf = (size_t)BB * PP;          // 558,848
    size_t off = 0;
    float* ovl   = (float*)(ws + off); off += 4 * npf;
    int*   obj   = (int*)  (ws + off); off += 4 * npf;
    float* ceneg = (float*)(ws + off); off += 4 * npf;   // 16B-aligned (npf*4 % 16 == 0)
    unsigned long long* part = (unsigned long long*)(ws + off); off += 8 * (size_t)BB * NBM * OO;
    float* pp_posce = (float*)(ws + off); off += 4 * (size_t)BB * NB2;
    float* pp_sl1   = (float*)(ws + off); off += 4 * (size_t)BB * NB2;
    int*   pp_np    = (int*)  (ws + off); off += 4 * (size_t)BB * NB2;
    float* posce_b  = (float*)(ws + off); off += 4 * BB;
    float* sl1_b    = (float*)(ws + off); off += 4 * BB;
    int*   n_pos    = (int*)  (ws + off); off += 4 * BB;
    float* hard     = (float*)(ws + off); off += 4 * BB;
    // no memset needed: part/pp_* are fully written before being read

    dim3 gM(NBM, BB);
    k_match<<<gM, 256, 0, stream>>>(gt_boxes, (const float4*)priors, ovl, obj, part);

    k_force<<<BB, 64, 0, stream>>>(part, ovl, obj);

    dim3 gB(NB2, BB);
    k_ce<<<gB, 256, 0, stream>>>(pred_scores, (const float4*)pred_locs, gt_boxes, gt_labels,
                                 (const float4*)priors, ovl, obj, ceneg,
                                 pp_posce, pp_sl1, pp_np);

    k_topk<<<BB, 512, 0, stream>>>(ceneg, pp_posce, pp_sl1, pp_np,
                                   hard, posce_b, sl1_b, n_pos);

    k_final<<<1, 64, 0, stream>>>(n_pos, hard, posce_b, sl1_b, (float*)d_out);
}